// Round 1
// baseline (166.436 us; speedup 1.0000x reference)
//
#include <hip/hip_runtime.h>
#include <stdint.h>

#define BB 4
#define CC 256
#define NN 4096
#define II 32
#define NT (NN/32)   // 128 K-steps in attention m-loop

typedef __attribute__((ext_vector_type(8))) short short8;
typedef __attribute__((ext_vector_type(4))) short short4v;
typedef __attribute__((ext_vector_type(4))) float float4v;

union U8 { short8 s8; unsigned u[4]; };

#define MFMA16(a,b,c) __builtin_amdgcn_mfma_f32_16x16x32_bf16(a,b,c,0,0,0)

__device__ inline unsigned short f2bf(float f){
  unsigned u = __float_as_uint(f);
  u += 0x7fffu + ((u >> 16) & 1u);
  return (unsigned short)(u >> 16);
}
__device__ inline unsigned pack2(float a, float b){
  return (unsigned)f2bf(a) | ((unsigned)f2bf(b) << 16);
}
__device__ inline short8 cvt8(float4v a, float4v b){
  U8 t;
  t.u[0] = pack2(a[0], a[1]); t.u[1] = pack2(a[2], a[3]);
  t.u[2] = pack2(b[0], b[1]); t.u[3] = pack2(b[2], b[3]);
  return t.s8;
}

// ---------------- kernel 1: x[b][c][n] f32 -> xt[b][n][c] bf16 ----------------
__global__ __launch_bounds__(256) void kxt(const float* __restrict__ x,
                                           unsigned short* __restrict__ xt){
  __shared__ float t[32][33];
  const int b = blockIdx.z, cb = blockIdx.y * 32, nb = blockIdx.x * 32;
  const int tid = threadIdx.x;
  const int rr = tid >> 3, q4 = (tid & 7) * 4;
  float4v v = *(const float4v*)(x + ((size_t)(b*CC + cb + rr))*NN + nb + q4);
  t[rr][q4+0] = v[0]; t[rr][q4+1] = v[1]; t[rr][q4+2] = v[2]; t[rr][q4+3] = v[3];
  __syncthreads();
  short4v o;
  o[0] = (short)f2bf(t[q4+0][rr]);
  o[1] = (short)f2bf(t[q4+1][rr]);
  o[2] = (short)f2bf(t[q4+2][rr]);
  o[3] = (short)f2bf(t[q4+3][rr]);
  *(short4v*)(xt + ((size_t)(b*NN + nb + rr))*CC + cb + q4) = o;
}

// ---------------- kernel 2: q,k projection ----------------
// q[b][n][i] = sum_c xt[b][n][c]*Wq[i][c] + bq[i]   (same for k)
__global__ __launch_bounds__(256) void kqk(const unsigned short* __restrict__ xt,
    const float* __restrict__ Wq, const float* __restrict__ bq,
    const float* __restrict__ Wk, const float* __restrict__ bk,
    unsigned short* __restrict__ qws, unsigned short* __restrict__ kws){
  const int tid = threadIdx.x, w = tid >> 6, lane = tid & 63;
  const int r = lane & 15, g = lane >> 4;
  const int gw = blockIdx.x * 4 + w;
  const int b = gw >> 8, nt = gw & 255, n0 = nt * 16;
  const unsigned short* abase = xt + ((size_t)(b*NN + n0 + r))*CC + g*8;
  float4v acc[4];
  float4v z4 = {0.f,0.f,0.f,0.f};
  #pragma unroll
  for (int ni = 0; ni < 4; ++ni) acc[ni] = z4;
  #pragma unroll
  for (int kk = 0; kk < 8; ++kk){
    short8 a = *(const short8*)(abase + kk*32);
    #pragma unroll
    for (int ni = 0; ni < 4; ++ni){
      const float* Wp = (ni < 2 ? Wq : Wk) + (size_t)((ni&1)*16 + r)*CC + kk*32 + g*8;
      short8 bf = cvt8(*(const float4v*)Wp, *(const float4v*)(Wp + 4));
      acc[ni] = MFMA16(a, bf, acc[ni]);
    }
  }
  #pragma unroll
  for (int ni = 0; ni < 4; ++ni){
    const float bias = (ni < 2 ? bq : bk)[(ni&1)*16 + r];
    unsigned short* dst = (ni < 2 ? qws : kws);
    #pragma unroll
    for (int rr = 0; rr < 4; ++rr){
      int n = n0 + g*4 + rr;
      dst[((size_t)b*NN + n)*II + (ni&1)*16 + r] = f2bf(acc[ni][rr] + bias);
    }
  }
}

// ---------------- kernel 3: v projection ----------------
// v[b][c][n] = sum_c' Wv[c][c']*xt[b][n][c'] + bv[c]
__global__ __launch_bounds__(256) void kvp(const unsigned short* __restrict__ xt,
    const float* __restrict__ Wv, const float* __restrict__ bv,
    unsigned short* __restrict__ vws){
  const int tid = threadIdx.x, w = tid >> 6, lane = tid & 63;
  const int r = lane & 15, g = lane >> 4;
  const int gw = blockIdx.x * 4 + w;
  const int b = gw >> 10, rest = gw & 1023;
  const int c0 = (rest >> 6) * 16, n0 = (rest & 63) * 64;
  float4v acc[4];
  float4v z4 = {0.f,0.f,0.f,0.f};
  #pragma unroll
  for (int ni = 0; ni < 4; ++ni) acc[ni] = z4;
  #pragma unroll
  for (int kk = 0; kk < 8; ++kk){
    const float* Wp = Wv + ((size_t)(c0 + r))*CC + kk*32 + g*8;
    short8 a = cvt8(*(const float4v*)Wp, *(const float4v*)(Wp + 4));
    #pragma unroll
    for (int ni = 0; ni < 4; ++ni){
      short8 bf = *(const short8*)(xt + ((size_t)(b*NN + n0 + ni*16 + r))*CC + kk*32 + g*8);
      acc[ni] = MFMA16(a, bf, acc[ni]);
    }
  }
  #pragma unroll
  for (int ni = 0; ni < 4; ++ni){
    #pragma unroll
    for (int rr = 0; rr < 4; ++rr){
      int c = c0 + g*4 + rr;
      vws[((size_t)b*CC + c)*NN + n0 + ni*16 + r] = f2bf(acc[ni][rr] + bv[c]);
    }
  }
}

// ---------------- kernel 4: fused flash attention + epilogue ----------------
// block: c-tile 128 (blockIdx.y) x n-tile 128 (blockIdx.x), batch z; 4 waves, wave w = n-cols [w*32,w*32+32)
__global__ __launch_bounds__(256) void kattn(
    const unsigned short* __restrict__ qws, const unsigned short* __restrict__ kws,
    const unsigned short* __restrict__ vws, const float* __restrict__ x,
    const float* __restrict__ gamma, float* __restrict__ out){
  __shared__ __align__(16) unsigned short vlds[2][128*32];
  const int tid = threadIdx.x, w = tid >> 6, lane = tid & 63;
  const int r = lane & 15, g = lane >> 4;
  const int b = blockIdx.z, c0 = blockIdx.y * 128, n0 = blockIdx.x * 128;
  const int nw0 = n0 + w * 32;

  // hoisted Q B-frags (loop-invariant): B[k=i][col=n], i contiguous
  short8 qf0 = *(const short8*)(qws + ((size_t)(b*NN + nw0 +      r))*II + g*8);
  short8 qf1 = *(const short8*)(qws + ((size_t)(b*NN + nw0 + 16 + r))*II + g*8);

  // permuted k-row index: S^T tile row R -> global m-local M0(R)=8*(R>>2)+(R&3); tile1 = +4.
  const int M0 = ((r >> 2) << 3) + (r & 3);
  const unsigned short* kbase = kws + ((size_t)b*NN + M0)*II + g*8;

  float4v acc[8][2];
  float4v z4 = {0.f,0.f,0.f,0.f};
  #pragma unroll
  for (int mi = 0; mi < 8; ++mi){ acc[mi][0] = z4; acc[mi][1] = z4; }
  float sacc0 = 0.f, sacc1 = 0.f;

  // V staging (reg-staged, XOR-swizzled LDS: seg' = sg ^ ((row>>1)&3) -> 2-way free)
  const unsigned short* vsrc = vws + ((size_t)b*CC + c0)*NN;
  const int row0 = tid >> 2, sg0 = tid & 3, row1 = row0 + 64;
  const int slot0 = row0*4 + (sg0 ^ ((row0 >> 1) & 3));
  const int slot1 = row1*4 + (sg0 ^ ((row1 >> 1) & 3));
  short8 st0 = *(const short8*)(vsrc + (size_t)row0*NN + sg0*8);
  short8 st1 = *(const short8*)(vsrc + (size_t)row1*NN + sg0*8);
  *(short8*)(vlds[0] + slot0*8) = st0;
  *(short8*)(vlds[0] + slot1*8) = st1;

  int vofs[8];
  #pragma unroll
  for (int mi = 0; mi < 8; ++mi){
    int row = mi*16 + r;
    vofs[mi] = (row*4 + (g ^ ((row >> 1) & 3)))*8;
  }

  for (int kt = 0; kt < NT; ++kt){
    __syncthreads();                       // vlds[kt&1] visible
    const int mb = kt * 32;
    if (kt + 1 < NT){                      // prefetch next V tile into regs
      st0 = *(const short8*)(vsrc + (size_t)row0*NN + (mb + 32) + sg0*8);
      st1 = *(const short8*)(vsrc + (size_t)row1*NN + (mb + 32) + sg0*8);
    }
    // K A-frags (global, L2-resident), permuted rows
    const unsigned short* kp = kbase + (size_t)mb*II;
    short8 kf0 = *(const short8*)(kp);
    short8 kf1 = *(const short8*)(kp + 4*II);
    // V A-frags from LDS
    const unsigned short* vb = vlds[kt & 1];
    short8 va[8];
    #pragma unroll
    for (int mi = 0; mi < 8; ++mi) va[mi] = *(const short8*)(vb + vofs[mi]);
    // S^T = mfma(K, Q): lane holds S[m = mb+8g+4t+rr][n = nw0+ni*16+r]
    float4v s00 = MFMA16(kf0, qf0, z4);
    float4v s01 = MFMA16(kf0, qf1, z4);
    float4v s10 = MFMA16(kf1, qf0, z4);
    float4v s11 = MFMA16(kf1, qf1, z4);
    // exp (no max shift: |s| bounded ~35, f32-safe), row-sum partials, bf16 pack in-lane
    float e0a = __expf(s00[0]), e0b = __expf(s00[1]), e0c = __expf(s00[2]), e0d = __expf(s00[3]);
    float e1a = __expf(s10[0]), e1b = __expf(s10[1]), e1c = __expf(s10[2]), e1d = __expf(s10[3]);
    sacc0 += (e0a + e0b + e0c + e0d) + (e1a + e1b + e1c + e1d);
    U8 bf0;
    bf0.u[0] = pack2(e0a, e0b); bf0.u[1] = pack2(e0c, e0d);
    bf0.u[2] = pack2(e1a, e1b); bf0.u[3] = pack2(e1c, e1d);
    float f0a = __expf(s01[0]), f0b = __expf(s01[1]), f0c = __expf(s01[2]), f0d = __expf(s01[3]);
    float f1a = __expf(s11[0]), f1b = __expf(s11[1]), f1c = __expf(s11[2]), f1d = __expf(s11[3]);
    sacc1 += (f0a + f0b + f0c + f0d) + (f1a + f1b + f1c + f1d);
    U8 bf1;
    bf1.u[0] = pack2(f0a, f0b); bf1.u[1] = pack2(f0c, f0d);
    bf1.u[2] = pack2(f1a, f1b); bf1.u[3] = pack2(f1c, f1d);
    // PV: acc[c-tile][n-tile] += v * P
    #pragma unroll
    for (int mi = 0; mi < 8; ++mi){
      acc[mi][0] = MFMA16(va[mi], bf0.s8, acc[mi][0]);
      acc[mi][1] = MFMA16(va[mi], bf1.s8, acc[mi][1]);
    }
    __syncthreads();                       // all waves done reading vlds[kt&1]
    if (kt + 1 < NT){
      *(short8*)(vlds[(kt+1)&1] + slot0*8) = st0;
      *(short8*)(vlds[(kt+1)&1] + slot1*8) = st1;
    }
  }

  // row sums: reduce over the 4 lanes sharing (l&15)
  float s0 = sacc0; s0 += __shfl_xor(s0, 16); s0 += __shfl_xor(s0, 32);
  float s1 = sacc1; s1 += __shfl_xor(s1, 16); s1 += __shfl_xor(s1, 32);
  const float inv0 = 1.0f / s0, inv1 = 1.0f / s1;
  const float gmv = gamma[0];
  #pragma unroll
  for (int mi = 0; mi < 8; ++mi){
    const int c = c0 + mi*16 + g*4;
    #pragma unroll
    for (int ni = 0; ni < 2; ++ni){
      const float inv = ni ? inv1 : inv0;
      const size_t base = ((size_t)b*CC + c)*NN + nw0 + ni*16 + r;
      float4v a = acc[mi][ni];
      #pragma unroll
      for (int rr = 0; rr < 4; ++rr){
        const size_t idx = base + (size_t)rr*NN;
        out[idx] = gmv * (a[rr] * inv) + x[idx];
      }
    }
  }
}

extern "C" void kernel_launch(void* const* d_in, const int* in_sizes, int n_in,
                              void* d_out, int out_size, void* d_ws, size_t ws_size,
                              hipStream_t stream){
  const float* x  = (const float*)d_in[0];
  const float* Wq = (const float*)d_in[1];
  const float* bq = (const float*)d_in[2];
  const float* Wk = (const float*)d_in[3];
  const float* bk = (const float*)d_in[4];
  const float* Wv = (const float*)d_in[5];
  const float* bv = (const float*)d_in[6];
  const float* gm = (const float*)d_in[7];
  float* out = (float*)d_out;

  unsigned short* xt  = (unsigned short*)d_ws;              // [B][N][C]  8 MB
  unsigned short* qws = xt  + (size_t)BB*NN*CC;             // [B][N][32] 1 MB
  unsigned short* kws = qws + (size_t)BB*NN*II;             // [B][N][32] 1 MB
  unsigned short* vws = kws + (size_t)BB*NN*II;             // [B][C][N]  8 MB

  kxt<<<dim3(NN/32, CC/32, BB), 256, 0, stream>>>(x, xt);
  kqk<<<dim3(BB*NN/16/4), 256, 0, stream>>>(xt, Wq, bq, Wk, bk, qws, kws);
  kvp<<<dim3(BB*(CC/16)*(NN/64)/4), 256, 0, stream>>>(xt, Wv, bv, vws);
  kattn<<<dim3(NN/128, 2, BB), 256, 0, stream>>>(qws, kws, vws, x, gm, out);
}

// Round 2
// 150.381 us; speedup vs baseline: 1.1068x; 1.1068x over previous
//
#include <hip/hip_runtime.h>
#include <stdint.h>

#define BB 4
#define CC 256
#define NN 4096
#define II 32
#define NT (NN/32)   // 128 K-steps in attention m-loop

typedef __attribute__((ext_vector_type(8))) short short8;
typedef __attribute__((ext_vector_type(4))) short short4v;
typedef __attribute__((ext_vector_type(4))) float float4v;

union U8 { short8 s8; unsigned u[4]; };

#define MFMA16(a,b,c) __builtin_amdgcn_mfma_f32_16x16x32_bf16(a,b,c,0,0,0)
#define LOG2E 1.4426950408889634f

__device__ inline unsigned short f2bf(float f){
  unsigned u = __float_as_uint(f);
  u += 0x7fffu + ((u >> 16) & 1u);
  return (unsigned short)(u >> 16);
}
__device__ inline unsigned pack2(float a, float b){
  return (unsigned)f2bf(a) | ((unsigned)f2bf(b) << 16);
}
__device__ inline short8 cvt8(float4v a, float4v b){
  U8 t;
  t.u[0] = pack2(a[0], a[1]); t.u[1] = pack2(a[2], a[3]);
  t.u[2] = pack2(b[0], b[1]); t.u[3] = pack2(b[2], b[3]);
  return t.s8;
}
__device__ inline unsigned cvtpk(float lo, float hi){
  unsigned r;
  asm("v_cvt_pk_bf16_f32 %0, %1, %2" : "=v"(r) : "v"(lo), "v"(hi));
  return r;
}

// ---------------- kernel 1: x[b][c][n] f32 -> xt[b][n][c] bf16 ----------------
__global__ __launch_bounds__(256) void kxt(const float* __restrict__ x,
                                           unsigned short* __restrict__ xt){
  __shared__ float t[32][33];
  const int b = blockIdx.z, cb = blockIdx.y * 32, nb = blockIdx.x * 32;
  const int tid = threadIdx.x;
  const int rr = tid >> 3, q4 = (tid & 7) * 4;
  float4v v = *(const float4v*)(x + ((size_t)(b*CC + cb + rr))*NN + nb + q4);
  t[rr][q4+0] = v[0]; t[rr][q4+1] = v[1]; t[rr][q4+2] = v[2]; t[rr][q4+3] = v[3];
  __syncthreads();
  short4v o;
  o[0] = (short)f2bf(t[q4+0][rr]);
  o[1] = (short)f2bf(t[q4+1][rr]);
  o[2] = (short)f2bf(t[q4+2][rr]);
  o[3] = (short)f2bf(t[q4+3][rr]);
  *(short4v*)(xt + ((size_t)(b*NN + nb + rr))*CC + cb + q4) = o;
}

// ---------------- kernel 2: q,k projection ----------------
// q[b][n][i] = (sum_c xt[b][n][c]*Wq[i][c] + bq[i]) * LOG2E   (k unscaled)
__global__ __launch_bounds__(256) void kqk(const unsigned short* __restrict__ xt,
    const float* __restrict__ Wq, const float* __restrict__ bq,
    const float* __restrict__ Wk, const float* __restrict__ bk,
    unsigned short* __restrict__ qws, unsigned short* __restrict__ kws){
  const int tid = threadIdx.x, w = tid >> 6, lane = tid & 63;
  const int r = lane & 15, g = lane >> 4;
  const int gw = blockIdx.x * 4 + w;
  const int b = gw >> 8, nt = gw & 255, n0 = nt * 16;
  const unsigned short* abase = xt + ((size_t)(b*NN + n0 + r))*CC + g*8;
  float4v acc[4];
  float4v z4 = {0.f,0.f,0.f,0.f};
  #pragma unroll
  for (int ni = 0; ni < 4; ++ni) acc[ni] = z4;
  #pragma unroll
  for (int kk = 0; kk < 8; ++kk){
    short8 a = *(const short8*)(abase + kk*32);
    #pragma unroll
    for (int ni = 0; ni < 4; ++ni){
      const float* Wp = (ni < 2 ? Wq : Wk) + (size_t)((ni&1)*16 + r)*CC + kk*32 + g*8;
      short8 bf = cvt8(*(const float4v*)Wp, *(const float4v*)(Wp + 4));
      acc[ni] = MFMA16(a, bf, acc[ni]);
    }
  }
  #pragma unroll
  for (int ni = 0; ni < 4; ++ni){
    const float bias = (ni < 2 ? bq : bk)[(ni&1)*16 + r];
    const float scale = (ni < 2) ? LOG2E : 1.0f;
    unsigned short* dst = (ni < 2 ? qws : kws);
    #pragma unroll
    for (int rr = 0; rr < 4; ++rr){
      int n = n0 + g*4 + rr;
      dst[((size_t)b*NN + n)*II + (ni&1)*16 + r] = f2bf((acc[ni][rr] + bias) * scale);
    }
  }
}

// ---------------- kernel 3: v projection ----------------
__global__ __launch_bounds__(256) void kvp(const unsigned short* __restrict__ xt,
    const float* __restrict__ Wv, const float* __restrict__ bv,
    unsigned short* __restrict__ vws){
  const int tid = threadIdx.x, w = tid >> 6, lane = tid & 63;
  const int r = lane & 15, g = lane >> 4;
  const int gw = blockIdx.x * 4 + w;
  const int b = gw >> 10, rest = gw & 1023;
  const int c0 = (rest >> 6) * 16, n0 = (rest & 63) * 64;
  float4v acc[4];
  float4v z4 = {0.f,0.f,0.f,0.f};
  #pragma unroll
  for (int ni = 0; ni < 4; ++ni) acc[ni] = z4;
  #pragma unroll
  for (int kk = 0; kk < 8; ++kk){
    const float* Wp = Wv + ((size_t)(c0 + r))*CC + kk*32 + g*8;
    short8 a = cvt8(*(const float4v*)Wp, *(const float4v*)(Wp + 4));
    #pragma unroll
    for (int ni = 0; ni < 4; ++ni){
      short8 bf = *(const short8*)(xt + ((size_t)(b*NN + n0 + ni*16 + r))*CC + kk*32 + g*8);
      acc[ni] = MFMA16(a, bf, acc[ni]);
    }
  }
  #pragma unroll
  for (int ni = 0; ni < 4; ++ni){
    #pragma unroll
    for (int rr = 0; rr < 4; ++rr){
      int c = c0 + g*4 + rr;
      vws[((size_t)b*CC + c)*NN + n0 + ni*16 + r] = f2bf(acc[ni][rr] + bv[c]);
    }
  }
}

// ---------------- kernel 4: fused flash attention + epilogue ----------------
// block: c-tile 128 (blockIdx.y) x n-tile 128 (blockIdx.x), batch z; 8 waves, wave w = n-cols [w*16, w*16+16)
__global__ __launch_bounds__(512) void kattn(
    const unsigned short* __restrict__ qws, const unsigned short* __restrict__ kws,
    const unsigned short* __restrict__ vws, const float* __restrict__ x,
    const float* __restrict__ gamma, float* __restrict__ out){
  __shared__ __align__(16) unsigned short vlds[2][128*32];
  const int tid = threadIdx.x, w = tid >> 6, lane = tid & 63;
  const int r = lane & 15, g = lane >> 4;
  const int b = blockIdx.z, c0 = blockIdx.y * 128, n0 = blockIdx.x * 128;
  const int nw0 = n0 + w * 16;

  // hoisted Q B-frag (loop-invariant): B[k=i][col=n], pre-scaled by log2e
  short8 qf = *(const short8*)(qws + ((size_t)(b*NN + nw0 + r))*II + g*8);

  // ones A-frag for row sums via MFMA
  U8 onesu; onesu.u[0] = 0x3F803F80u; onesu.u[1] = 0x3F803F80u;
  onesu.u[2] = 0x3F803F80u; onesu.u[3] = 0x3F803F80u;
  const short8 ones8 = onesu.s8;

  // permuted k-row index: S^T tile row R -> m-local M0(R)=8*(R>>2)+(R&3); tile1 = +4.
  const int M0 = ((r >> 2) << 3) + (r & 3);
  const unsigned short* kbase = kws + ((size_t)b*NN + M0)*II + g*8;

  float4v z4 = {0.f,0.f,0.f,0.f};
  float4v acc[8];
  #pragma unroll
  for (int mi = 0; mi < 8; ++mi) acc[mi] = z4;
  float4v accs = z4;

  // V staging (reg-staged, XOR-swizzled LDS: seg' = sg ^ ((row>>1)&3) -> 2-way free)
  const unsigned short* vsrc = vws + ((size_t)b*CC + c0)*NN;
  const int row0 = tid >> 2, sg0 = tid & 3;
  const int slot0 = row0*4 + (sg0 ^ ((row0 >> 1) & 3));
  short8 st0 = *(const short8*)(vsrc + (size_t)row0*NN + sg0*8);
  *(short8*)(vlds[0] + slot0*8) = st0;

  int vofs[8];
  #pragma unroll
  for (int mi = 0; mi < 8; ++mi){
    int row = mi*16 + r;
    vofs[mi] = (row*4 + (g ^ ((row >> 1) & 3)))*8;
  }

  // preload K frags for kt=0
  short8 kf0 = *(const short8*)(kbase);
  short8 kf1 = *(const short8*)(kbase + 4*II);
  short8 kf0n, kf1n;

  for (int kt = 0; kt < NT; ++kt){
    __syncthreads();                       // vlds[kt&1] visible
    const int mb = kt * 32;
    if (kt + 1 < NT){                      // prefetch next V tile + K frags
      st0  = *(const short8*)(vsrc + (size_t)row0*NN + (mb + 32) + sg0*8);
      const unsigned short* kp = kbase + (size_t)(mb + 32)*II;
      kf0n = *(const short8*)(kp);
      kf1n = *(const short8*)(kp + 4*II);
    }
    // V A-frags from LDS
    const unsigned short* vb = vlds[kt & 1];
    short8 va[8];
    #pragma unroll
    for (int mi = 0; mi < 8; ++mi) va[mi] = *(const short8*)(vb + vofs[mi]);
    // S^T = mfma(K, Q): lane holds S[m = mb+8g+4t+rr][n = nw0+r] * log2e
    float4v s0 = MFMA16(kf0, qf, z4);
    float4v s1 = MFMA16(kf1, qf, z4);
    // exp2 (q pre-scaled; no max shift needed, |s| bounded ~50 in exp2 domain)
    float e0 = __builtin_exp2f(s0[0]), e1 = __builtin_exp2f(s0[1]);
    float e2 = __builtin_exp2f(s0[2]), e3 = __builtin_exp2f(s0[3]);
    float e4 = __builtin_exp2f(s1[0]), e5 = __builtin_exp2f(s1[1]);
    float e6 = __builtin_exp2f(s1[2]), e7 = __builtin_exp2f(s1[3]);
    U8 bf;
    bf.u[0] = cvtpk(e0, e1); bf.u[1] = cvtpk(e2, e3);
    bf.u[2] = cvtpk(e4, e5); bf.u[3] = cvtpk(e6, e7);
    // row sums via ones-MFMA: accs[*] = sum_m P[m][n=r] (broadcast over rows)
    accs = MFMA16(ones8, bf.s8, accs);
    // PV: acc[c-tile] += v * P
    #pragma unroll
    for (int mi = 0; mi < 8; ++mi)
      acc[mi] = MFMA16(va[mi], bf.s8, acc[mi]);
    __syncthreads();                       // all waves done reading vlds[kt&1]
    if (kt + 1 < NT){
      *(short8*)(vlds[(kt+1)&1] + slot0*8) = st0;
      kf0 = kf0n; kf1 = kf1n;
    }
  }

  const float inv = 1.0f / accs[0];
  const float gmv = gamma[0];
  #pragma unroll
  for (int mi = 0; mi < 8; ++mi){
    const int c = c0 + mi*16 + g*4;
    const size_t base = ((size_t)b*CC + c)*NN + nw0 + r;
    float4v a = acc[mi];
    #pragma unroll
    for (int rr = 0; rr < 4; ++rr){
      const size_t idx = base + (size_t)rr*NN;
      out[idx] = gmv * (a[rr] * inv) + x[idx];
    }
  }
}

extern "C" void kernel_launch(void* const* d_in, const int* in_sizes, int n_in,
                              void* d_out, int out_size, void* d_ws, size_t ws_size,
                              hipStream_t stream){
  const float* x  = (const float*)d_in[0];
  const float* Wq = (const float*)d_in[1];
  const float* bq = (const float*)d_in[2];
  const float* Wk = (const float*)d_in[3];
  const float* bk = (const float*)d_in[4];
  const float* Wv = (const float*)d_in[5];
  const float* bv = (const float*)d_in[6];
  const float* gm = (const float*)d_in[7];
  float* out = (float*)d_out;

  unsigned short* xt  = (unsigned short*)d_ws;              // [B][N][C]  8 MB
  unsigned short* qws = xt  + (size_t)BB*NN*CC;             // [B][N][32] 1 MB
  unsigned short* kws = qws + (size_t)BB*NN*II;             // [B][N][32] 1 MB
  unsigned short* vws = kws + (size_t)BB*NN*II;             // [B][C][N]  8 MB

  kxt<<<dim3(NN/32, CC/32, BB), 256, 0, stream>>>(x, xt);
  kqk<<<dim3(BB*NN/16/4), 256, 0, stream>>>(xt, Wq, bq, Wk, bk, qws, kws);
  kvp<<<dim3(BB*(CC/16)*(NN/64)/4), 256, 0, stream>>>(xt, Wv, bv, vws);
  kattn<<<dim3(NN/128, 2, BB), 512, 0, stream>>>(qws, kws, vws, x, gm, out);
}

// Round 3
// 113.113 us; speedup vs baseline: 1.4714x; 1.3295x over previous
//
#include <hip/hip_runtime.h>
#include <stdint.h>

#define BB 4
#define CC 256
#define NN 4096
#define II 32
#define NS (NN/64)   // 64 super-steps; each covers 64 m (32 per wave-parity)

typedef __attribute__((ext_vector_type(8))) short short8;
typedef __attribute__((ext_vector_type(4))) short short4v;
typedef __attribute__((ext_vector_type(4))) float float4v;

union U8 { short8 s8; unsigned u[4]; };

#define MFMA16(a,b,c) __builtin_amdgcn_mfma_f32_16x16x32_bf16(a,b,c,0,0,0)
#define LOG2E 1.4426950408889634f

__device__ inline unsigned short f2bf(float f){
  unsigned u = __float_as_uint(f);
  u += 0x7fffu + ((u >> 16) & 1u);
  return (unsigned short)(u >> 16);
}
__device__ inline unsigned pack2(float a, float b){
  return (unsigned)f2bf(a) | ((unsigned)f2bf(b) << 16);
}
__device__ inline short8 cvt8(float4v a, float4v b){
  U8 t;
  t.u[0] = pack2(a[0], a[1]); t.u[1] = pack2(a[2], a[3]);
  t.u[2] = pack2(b[0], b[1]); t.u[3] = pack2(b[2], b[3]);
  return t.s8;
}
__device__ inline unsigned cvtpk(float lo, float hi){
  unsigned r;
  asm("v_cvt_pk_bf16_f32 %0, %1, %2" : "=v"(r) : "v"(lo), "v"(hi));
  return r;
}

// ---------------- kernel 1: x[b][c][n] f32 -> xt[b][n][c] bf16 ----------------
__global__ __launch_bounds__(256) void kxt(const float* __restrict__ x,
                                           unsigned short* __restrict__ xt){
  __shared__ float t[32][33];
  const int b = blockIdx.z, cb = blockIdx.y * 32, nb = blockIdx.x * 32;
  const int tid = threadIdx.x;
  const int rr = tid >> 3, q4 = (tid & 7) * 4;
  float4v v = *(const float4v*)(x + ((size_t)(b*CC + cb + rr))*NN + nb + q4);
  t[rr][q4+0] = v[0]; t[rr][q4+1] = v[1]; t[rr][q4+2] = v[2]; t[rr][q4+3] = v[3];
  __syncthreads();
  short4v o;
  o[0] = (short)f2bf(t[q4+0][rr]);
  o[1] = (short)f2bf(t[q4+1][rr]);
  o[2] = (short)f2bf(t[q4+2][rr]);
  o[3] = (short)f2bf(t[q4+3][rr]);
  *(short4v*)(xt + ((size_t)(b*NN + nb + rr))*CC + cb + q4) = o;
}

// ---------------- kernel 2: q,k projection ----------------
// q[b][n][i] = (sum_c xt[b][n][c]*Wq[i][c] + bq[i]) * LOG2E   (k unscaled)
__global__ __launch_bounds__(256) void kqk(const unsigned short* __restrict__ xt,
    const float* __restrict__ Wq, const float* __restrict__ bq,
    const float* __restrict__ Wk, const float* __restrict__ bk,
    unsigned short* __restrict__ qws, unsigned short* __restrict__ kws){
  const int tid = threadIdx.x, w = tid >> 6, lane = tid & 63;
  const int r = lane & 15, g = lane >> 4;
  const int gw = blockIdx.x * 4 + w;
  const int b = gw >> 8, nt = gw & 255, n0 = nt * 16;
  const unsigned short* abase = xt + ((size_t)(b*NN + n0 + r))*CC + g*8;
  float4v acc[4];
  float4v z4 = {0.f,0.f,0.f,0.f};
  #pragma unroll
  for (int ni = 0; ni < 4; ++ni) acc[ni] = z4;
  #pragma unroll
  for (int kk = 0; kk < 8; ++kk){
    short8 a = *(const short8*)(abase + kk*32);
    #pragma unroll
    for (int ni = 0; ni < 4; ++ni){
      const float* Wp = (ni < 2 ? Wq : Wk) + (size_t)((ni&1)*16 + r)*CC + kk*32 + g*8;
      short8 bf = cvt8(*(const float4v*)Wp, *(const float4v*)(Wp + 4));
      acc[ni] = MFMA16(a, bf, acc[ni]);
    }
  }
  #pragma unroll
  for (int ni = 0; ni < 4; ++ni){
    const float bias = (ni < 2 ? bq : bk)[(ni&1)*16 + r];
    const float scale = (ni < 2) ? LOG2E : 1.0f;
    unsigned short* dst = (ni < 2 ? qws : kws);
    #pragma unroll
    for (int rr = 0; rr < 4; ++rr){
      int n = n0 + g*4 + rr;
      dst[((size_t)b*NN + n)*II + (ni&1)*16 + r] = f2bf((acc[ni][rr] + bias) * scale);
    }
  }
}

// ---------------- kernel 3: v projection ----------------
__global__ __launch_bounds__(256) void kvp(const unsigned short* __restrict__ xt,
    const float* __restrict__ Wv, const float* __restrict__ bv,
    unsigned short* __restrict__ vws){
  const int tid = threadIdx.x, w = tid >> 6, lane = tid & 63;
  const int r = lane & 15, g = lane >> 4;
  const int gw = blockIdx.x * 4 + w;
  const int b = gw >> 10, rest = gw & 1023;
  const int c0 = (rest >> 6) * 16, n0 = (rest & 63) * 64;
  float4v acc[4];
  float4v z4 = {0.f,0.f,0.f,0.f};
  #pragma unroll
  for (int ni = 0; ni < 4; ++ni) acc[ni] = z4;
  #pragma unroll
  for (int kk = 0; kk < 8; ++kk){
    const float* Wp = Wv + ((size_t)(c0 + r))*CC + kk*32 + g*8;
    short8 a = cvt8(*(const float4v*)Wp, *(const float4v*)(Wp + 4));
    #pragma unroll
    for (int ni = 0; ni < 4; ++ni){
      short8 bf = *(const short8*)(xt + ((size_t)(b*NN + n0 + ni*16 + r))*CC + kk*32 + g*8);
      acc[ni] = MFMA16(a, bf, acc[ni]);
    }
  }
  #pragma unroll
  for (int ni = 0; ni < 4; ++ni){
    #pragma unroll
    for (int rr = 0; rr < 4; ++rr){
      int c = c0 + g*4 + rr;
      vws[((size_t)b*CC + c)*NN + n0 + ni*16 + r] = f2bf(acc[ni][rr] + bv[c]);
    }
  }
}

// ---------------- kernel 4: fused flash attention + epilogue ----------------
// block: c-tile 128 (blockIdx.y) x n-tile 64 (blockIdx.x), batch z; 8 waves.
// wave w: nsub = w&3 -> n-cols [nsub*16, nsub*16+16); p = w>>2 -> m-parity
// (p=0: m in [s*64, s*64+32), p=1: m in [s*64+32, s*64+64)); partial results
// combined via LDS at the end.
union SMem {
  unsigned short v[2][2][128*32];   // [dbuf][parity][c=128][m=32] swizzled
  float comb[4][64][33];            // [nsub][lane][acc0..31, rowsum]
};

__global__ __launch_bounds__(512, 4) void kattn(
    const unsigned short* __restrict__ qws, const unsigned short* __restrict__ kws,
    const unsigned short* __restrict__ vws, const float* __restrict__ x,
    const float* __restrict__ gamma, float* __restrict__ out){
  __shared__ __align__(16) SMem sm;
  const int tid = threadIdx.x, w = tid >> 6, lane = tid & 63;
  const int r = lane & 15, g = lane >> 4;
  const int nsub = w & 3, p = w >> 2;
  const int b = blockIdx.z, c0 = blockIdx.y * 128, n0 = blockIdx.x * 64;
  const int nw0 = n0 + nsub * 16;

  // hoisted Q B-frag (loop-invariant), pre-scaled by log2e
  short8 qf = *(const short8*)(qws + ((size_t)(b*NN + nw0 + r))*II + g*8);

  // ones A-frag for row sums via MFMA
  U8 onesu; onesu.u[0] = 0x3F803F80u; onesu.u[1] = 0x3F803F80u;
  onesu.u[2] = 0x3F803F80u; onesu.u[3] = 0x3F803F80u;
  const short8 ones8 = onesu.s8;

  // permuted k-row index: S^T tile row R -> m-local M0(R)=8*(R>>2)+(R&3); tile1 = +4.
  const int M0 = ((r >> 2) << 3) + (r & 3);
  const unsigned short* kbase = kws + ((size_t)b*NN + M0)*II + g*8 + (size_t)(p*32)*II;

  float4v z4 = {0.f,0.f,0.f,0.f};
  float4v acc[8];
  #pragma unroll
  for (int mi = 0; mi < 8; ++mi) acc[mi] = z4;
  float4v accs = z4;

  // V staging: thread t stages 16B of each parity tile. XOR swizzle on m-segment.
  const unsigned short* vsrc = vws + ((size_t)b*CC + c0)*NN;
  const int row0 = tid >> 2, sg0 = tid & 3;
  const int slot0 = (row0*4 + (sg0 ^ ((row0 >> 1) & 3))) * 8;
  short8 stE = *(const short8*)(vsrc + (size_t)row0*NN + sg0*8);
  short8 stO = *(const short8*)(vsrc + (size_t)row0*NN + 32 + sg0*8);
  *(short8*)(&sm.v[0][0][slot0]) = stE;
  *(short8*)(&sm.v[0][1][slot0]) = stO;

  // V read base: swizzle g^((row>>1)&3) is mi-independent for row=mi*16+r
  const int vbase = (r*4 + (g ^ ((r >> 1) & 3))) * 8;

  // preload K frags for s=0 (this wave's parity chunk)
  short8 kf0 = *(const short8*)(kbase);
  short8 kf1 = *(const short8*)(kbase + 4*II);
  short8 kf0n, kf1n;

  for (int s = 0; s < NS; ++s){
    __syncthreads();                       // sm.v[s&1] ready
    const int mb = s * 64;
    if (s + 1 < NS){                       // prefetch next super-step V + K
      stE = *(const short8*)(vsrc + (size_t)row0*NN + (mb + 64) + sg0*8);
      stO = *(const short8*)(vsrc + (size_t)row0*NN + (mb + 96) + sg0*8);
      const unsigned short* kp = kbase + (size_t)(mb + 64)*II;
      kf0n = *(const short8*)(kp);
      kf1n = *(const short8*)(kp + 4*II);
    }
    // V A-frags from LDS (constant offsets off one base)
    const unsigned short* vb = sm.v[s & 1][p] + vbase;
    short8 va[8];
    #pragma unroll
    for (int mi = 0; mi < 8; ++mi) va[mi] = *(const short8*)(vb + mi*512);
    // S^T = mfma(K, Q): lane holds S[m][n=nw0+r] * log2e for this wave's 32-m chunk
    float4v s0 = MFMA16(kf0, qf, z4);
    float4v s1 = MFMA16(kf1, qf, z4);
    float e0 = __builtin_exp2f(s0[0]), e1 = __builtin_exp2f(s0[1]);
    float e2 = __builtin_exp2f(s0[2]), e3 = __builtin_exp2f(s0[3]);
    float e4 = __builtin_exp2f(s1[0]), e5 = __builtin_exp2f(s1[1]);
    float e6 = __builtin_exp2f(s1[2]), e7 = __builtin_exp2f(s1[3]);
    U8 bf;
    bf.u[0] = cvtpk(e0, e1); bf.u[1] = cvtpk(e2, e3);
    bf.u[2] = cvtpk(e4, e5); bf.u[3] = cvtpk(e6, e7);
    // partial row sums via ones-MFMA (broadcast over rows)
    accs = MFMA16(ones8, bf.s8, accs);
    // PV: acc[c-tile] += v * P
    #pragma unroll
    for (int mi = 0; mi < 8; ++mi)
      acc[mi] = MFMA16(va[mi], bf.s8, acc[mi]);
    __syncthreads();                       // all waves done reading sm.v[s&1]
    if (s + 1 < NS){
      *(short8*)(&sm.v[(s+1)&1][0][slot0]) = stE;
      *(short8*)(&sm.v[(s+1)&1][1][slot0]) = stO;
      kf0 = kf0n; kf1 = kf1n;
    }
  }

  // combine parity halves via LDS (reuse V buffers; last barrier already passed)
  if (p == 1){
    float* cb = sm.comb[nsub][lane];
    #pragma unroll
    for (int mi = 0; mi < 8; ++mi)
      #pragma unroll
      for (int rr = 0; rr < 4; ++rr) cb[mi*4 + rr] = acc[mi][rr];
    cb[32] = accs[0];
  }
  __syncthreads();
  if (p == 0){
    const float* cb = sm.comb[nsub][lane];
    #pragma unroll
    for (int mi = 0; mi < 8; ++mi)
      #pragma unroll
      for (int rr = 0; rr < 4; ++rr) acc[mi][rr] += cb[mi*4 + rr];
    const float inv = 1.0f / (accs[0] + cb[32]);
    const float gmv = gamma[0];
    #pragma unroll
    for (int mi = 0; mi < 8; ++mi){
      const int c = c0 + mi*16 + g*4;
      const size_t base = ((size_t)b*CC + c)*NN + nw0 + r;
      float4v a = acc[mi];
      #pragma unroll
      for (int rr = 0; rr < 4; ++rr){
        const size_t idx = base + (size_t)rr*NN;
        out[idx] = gmv * (a[rr] * inv) + x[idx];
      }
    }
  }
}

extern "C" void kernel_launch(void* const* d_in, const int* in_sizes, int n_in,
                              void* d_out, int out_size, void* d_ws, size_t ws_size,
                              hipStream_t stream){
  const float* x  = (const float*)d_in[0];
  const float* Wq = (const float*)d_in[1];
  const float* bq = (const float*)d_in[2];
  const float* Wk = (const float*)d_in[3];
  const float* bk = (const float*)d_in[4];
  const float* Wv = (const float*)d_in[5];
  const float* bv = (const float*)d_in[6];
  const float* gm = (const float*)d_in[7];
  float* out = (float*)d_out;

  unsigned short* xt  = (unsigned short*)d_ws;              // [B][N][C]  8 MB
  unsigned short* qws = xt  + (size_t)BB*NN*CC;             // [B][N][32] 1 MB
  unsigned short* kws = qws + (size_t)BB*NN*II;             // [B][N][32] 1 MB
  unsigned short* vws = kws + (size_t)BB*NN*II;             // [B][C][N]  8 MB

  kxt<<<dim3(NN/32, CC/32, BB), 256, 0, stream>>>(x, xt);
  kqk<<<dim3(BB*NN/16/4), 256, 0, stream>>>(xt, Wq, bq, Wk, bk, qws, kws);
  kvp<<<dim3(BB*(CC/16)*(NN/64)/4), 256, 0, stream>>>(xt, Wv, bv, vws);
  kattn<<<dim3(NN/64, 2, BB), 512, 0, stream>>>(qws, kws, vws, x, gm, out);
}